// Round 4
// baseline (102.472 us; speedup 1.0000x reference)
//
#include <hip/hip_runtime.h>

#define B_   4
#define H_   64
#define W_   64
#define C_   256
#define HO_  58
#define WO_  58
#define TI_  29     // 2-row tiles (58 = 2*29)
#define TJ_  8      // 8-col tiles: j0 = 0,8,...,48,50 (last overlaps)
#define GRID (B_ * TI_ * TJ_)   // 928 = 8 * 116

typedef __attribute__((ext_vector_type(8))) short bf16x8;   // 8 bf16 = 4 VGPR
typedef __attribute__((ext_vector_type(4))) float f32x4;

// Truncation-split two fp32 into packed hi/lo bf16 dwords.
// hi = top 16 bits (exact bf16); rem = x - hi_f32 is exact; lo = trunc16(rem).
// Dropped lo*lo in 3-pass products => ~2^-16 relative error (fp32-level).
__device__ __forceinline__ void split2(float a, float b, unsigned& hi, unsigned& lo) {
    unsigned ua = __builtin_bit_cast(unsigned, a);
    unsigned ub = __builtin_bit_cast(unsigned, b);
    hi = (ua >> 16) | (ub & 0xFFFF0000u);
    float ra = a - __builtin_bit_cast(float, ua & 0xFFFF0000u);
    float rb = b - __builtin_bit_cast(float, ub & 0xFFFF0000u);
    lo = (__builtin_bit_cast(unsigned, ra) >> 16) |
         (__builtin_bit_cast(unsigned, rb) & 0xFFFF0000u);
}

// Fragment load: row-major [row][K] bf16 array, 8 contiguous K elems per lane.
// XOR swizzle (G4) kills the 16-way bank conflict of power-of-2 row strides.
__device__ __forceinline__ bf16x8 ldfrag(const short* arr, int row, int col, int rowBytes) {
    int byte = (row * rowBytes + col * 2) ^ ((row & 7) << 4);
    return *(const bf16x8*)((const char*)arr + byte);
}

__global__ __launch_bounds__(256, 3) void convnd_attn_kernel(const float* __restrict__ X,
                                                             float* __restrict__ out) {
    // ~49 KB total -> 3 blocks/CU
    __shared__ __align__(16) short UVh[128 * 64];   // 16 KB: U[128 cells][64 ch] or Vt[64 ch][128 cells]
    __shared__ __align__(16) short UVl[128 * 64];   // 16 KB (lo part)
    __shared__ __align__(16) short Wh[16 * 128];    // 4 KB: weights hi [px][cell]
    __shared__ __align__(16) short Wl[16 * 128];    // 4 KB
    __shared__ __align__(16) float SQ[128 * 16];    // 8 KB: S[cell][px]; aliases Qhi/Qlo
    __shared__ float psum[256];
    __shared__ float rtot[16];
    short* Qhi = (short*)SQ;            // [16 px][64 ch], 2 KB
    short* Qlo = Qhi + 16 * 64;         // 2 KB
    float* S   = SQ;                    // [128 cell][16 px]

    // XCD-contiguous swizzle (928 = 8*116, exact)
    const int sp  = (blockIdx.x & 7) * 116 + (blockIdx.x >> 3);
    const int tj  = sp & 7;
    const int rst = sp >> 3;
    const int ti  = rst % TI_;
    const int b   = rst / TI_;
    const int i0  = ti * 2;
    const int j0  = (tj < 7) ? tj * 8 : 50;   // last j-tile overlaps (benign dup writes)

    const int tid  = threadIdx.x;
    const int wave = tid >> 6;
    const int lane = tid & 63;
    const int lr   = lane & 15;           // fragment row index (m or n)
    const int kb8  = (lane >> 4) << 3;    // k-block offset within K=32

    const float* base = X + (size_t)b * (H_ * W_ * C_);

    // ---------------- Phase 1: QK^T, K(ch)-chunked, 3-pass split-bf16 ----------------
    f32x4 accS0 = {0.f, 0.f, 0.f, 0.f};
    f32x4 accS1 = {0.f, 0.f, 0.f, 0.f};

    // staging assignment (constant across chunks)
    const int ucell = tid >> 1;                 // 0..127
    const int uhalf = (tid & 1) << 5;           // ch 0 or 32
    const int ur = ucell >> 4, uc = ucell & 15;
    const int ucol = min(j0 + uc, 63);          // pad cols clamp (masked later)
    const float* usrc0 = base + (((i0 + ur) * W_) + ucol) * C_ + uhalf;
    const int urb = ucell * 128 + uhalf * 2;    // row byte base in U
    const int usw = (ucell & 7) << 4;

    const int qpx = tid >> 4;                   // 0..15
    const int qc4 = (tid & 15) << 2;            // ch 0..60
    const int qa = qpx >> 3, qb = qpx & 7;
    const float* qsrc0 = base + (((i0 + qa + 3) * W_) + (j0 + qb + 3)) * C_ + qc4;
    const int qrb = qpx * 128 + qc4 * 2;
    const int qsw = (qpx & 7) << 4;

    #pragma unroll
    for (int kc = 0; kc < 4; ++kc) {
        // stage U[128 cells][64 ch] (hi/lo split)
        {
            const float* src = usrc0 + kc * 64;
            float4 xx[8];
            #pragma unroll
            for (int e = 0; e < 8; ++e) xx[e] = *(const float4*)(src + e * 4);
            #pragma unroll
            for (int g = 0; g < 4; ++g) {
                uint4 hi, lo;
                split2(xx[g*2].x,   xx[g*2].y,   hi.x, lo.x);
                split2(xx[g*2].z,   xx[g*2].w,   hi.y, lo.y);
                split2(xx[g*2+1].x, xx[g*2+1].y, hi.z, lo.z);
                split2(xx[g*2+1].z, xx[g*2+1].w, hi.w, lo.w);
                *(uint4*)((char*)UVh + ((urb + g * 16) ^ usw)) = hi;
                *(uint4*)((char*)UVl + ((urb + g * 16) ^ usw)) = lo;
            }
        }
        // stage Q[16 px][64 ch], pre-scaled by 1/16
        {
            float4 qx = *(const float4*)(qsrc0 + kc * 64);
            qx.x *= 0.0625f; qx.y *= 0.0625f; qx.z *= 0.0625f; qx.w *= 0.0625f;
            unsigned h0, l0, h1, l1;
            split2(qx.x, qx.y, h0, l0);
            split2(qx.z, qx.w, h1, l1);
            *(uint2*)((char*)Qhi + (qrb ^ qsw)) = make_uint2(h0, h1);
            *(uint2*)((char*)Qlo + (qrb ^ qsw)) = make_uint2(l0, l1);
        }
        __syncthreads();

        // MFMA: S^T[cell][px]; wave owns cell-tiles 2w, 2w+1
        #pragma unroll
        for (int ks = 0; ks < 2; ++ks) {
            const int kcol = ks * 32 + kb8;
            bf16x8 qh = ldfrag(Qhi, lr, kcol, 128);
            bf16x8 ql = ldfrag(Qlo, lr, kcol, 128);
            {
                const int crow = (wave * 2 + 0) * 16 + lr;
                bf16x8 uh = ldfrag(UVh, crow, kcol, 128);
                bf16x8 ul = ldfrag(UVl, crow, kcol, 128);
                accS0 = __builtin_amdgcn_mfma_f32_16x16x32_bf16(uh, qh, accS0, 0, 0, 0);
                accS0 = __builtin_amdgcn_mfma_f32_16x16x32_bf16(uh, ql, accS0, 0, 0, 0);
                accS0 = __builtin_amdgcn_mfma_f32_16x16x32_bf16(ul, qh, accS0, 0, 0, 0);
            }
            {
                const int crow = (wave * 2 + 1) * 16 + lr;
                bf16x8 uh = ldfrag(UVh, crow, kcol, 128);
                bf16x8 ul = ldfrag(UVl, crow, kcol, 128);
                accS1 = __builtin_amdgcn_mfma_f32_16x16x32_bf16(uh, qh, accS1, 0, 0, 0);
                accS1 = __builtin_amdgcn_mfma_f32_16x16x32_bf16(uh, ql, accS1, 0, 0, 0);
                accS1 = __builtin_amdgcn_mfma_f32_16x16x32_bf16(ul, qh, accS1, 0, 0, 0);
            }
        }
        __syncthreads();   // before next chunk overwrites U/Q
    }

    // ---------------- Phase 2: write S (aliases dead Q), softmax, W hi/lo ----------------
    {
        const int mrow = (lane >> 4) << 2;   // C/D: row = (lane>>4)*4 + reg
        #pragma unroll
        for (int rr = 0; rr < 4; ++rr) {
            S[((wave * 2 + 0) * 16 + mrow + rr) * 16 + lr] = accS0[rr];
            S[((wave * 2 + 1) * 16 + mrow + rr) * 16 + lr] = accS1[rr];
        }
    }
    __syncthreads();

    const int spx = tid & 15, seg = tid >> 4;
    {
        const int sa = spx >> 3, sb = spx & 7;
        float e[8]; float ps = 0.f;
        #pragma unroll
        for (int k = 0; k < 8; ++k) {
            const int cell = seg * 8 + k;
            const int cr = cell >> 4, cc = cell & 15;
            const int di = cr - sa, dj = cc - sb;
            const bool valid = (di >= 0) & (di <= 6) & (dj >= 0) & (dj <= 6)
                               & !((di == 3) & (dj == 3));
            e[k] = valid ? __expf(S[cell * 16 + spx]) : 0.f;
            ps += e[k];
        }
        psum[seg * 16 + spx] = ps;
        __syncthreads();
        if (tid < 16) {
            float t = 0.f;
            #pragma unroll
            for (int s2 = 0; s2 < 16; ++s2) t += psum[s2 * 16 + tid];
            rtot[tid] = 1.0f / t;
        }
        __syncthreads();
        const float rt = rtot[spx];
        unsigned h0,h1,h2,h3, l0,l1,l2,l3;
        split2(e[0]*rt, e[1]*rt, h0, l0);
        split2(e[2]*rt, e[3]*rt, h1, l1);
        split2(e[4]*rt, e[5]*rt, h2, l2);
        split2(e[6]*rt, e[7]*rt, h3, l3);
        const int wb = (spx * 256 + seg * 16) ^ ((spx & 7) << 4);
        *(uint4*)((char*)Wh + wb) = make_uint4(h0, h1, h2, h3);
        *(uint4*)((char*)Wl + wb) = make_uint4(l0, l1, l2, l3);
    }
    __syncthreads();

    // ---------------- Phase 3: PV, N(ch)-chunked; V re-staged transposed ----------------
    const int cp  = tid & 63;              // cell pair (cells 2cp, 2cp+1)
    const int chg = (tid >> 6) << 4;       // ch group 0,16,32,48 (== wave*16)
    const int vr = (cp * 2) >> 4, vc = (cp * 2) & 15;
    const int vcol0 = min(j0 + vc, 63);
    const int vcol1 = min(j0 + vc + 1, 63);
    const float* vsrc0 = base + (((i0 + vr) * W_) + vcol0) * C_ + chg;
    const float* vsrc1 = base + (((i0 + vr) * W_) + vcol1) * C_ + chg;

    #pragma unroll
    for (int nc = 0; nc < 4; ++nc) {
        // stage Vt[64 ch][128 cells] (hi/lo), cell-pair packed dword writes
        {
            float4 y0[4], y1[4];
            #pragma unroll
            for (int e = 0; e < 4; ++e) {
                y0[e] = *(const float4*)(vsrc0 + nc * 64 + e * 4);
                y1[e] = *(const float4*)(vsrc1 + nc * 64 + e * 4);
            }
            #pragma unroll
            for (int jj = 0; jj < 4; ++jj) {
                const int chb = chg + jj * 4;
                unsigned h, l;
                split2(y0[jj].x, y1[jj].x, h, l);
                { int by = ((chb+0) * 256 + cp * 4) ^ (((chb+0) & 7) << 4);
                  *(unsigned*)((char*)UVh + by) = h; *(unsigned*)((char*)UVl + by) = l; }
                split2(y0[jj].y, y1[jj].y, h, l);
                { int by = ((chb+1) * 256 + cp * 4) ^ (((chb+1) & 7) << 4);
                  *(unsigned*)((char*)UVh + by) = h; *(unsigned*)((char*)UVl + by) = l; }
                split2(y0[jj].z, y1[jj].z, h, l);
                { int by = ((chb+2) * 256 + cp * 4) ^ (((chb+2) & 7) << 4);
                  *(unsigned*)((char*)UVh + by) = h; *(unsigned*)((char*)UVl + by) = l; }
                split2(y0[jj].w, y1[jj].w, h, l);
                { int by = ((chb+3) * 256 + cp * 4) ^ (((chb+3) & 7) << 4);
                  *(unsigned*)((char*)UVh + by) = h; *(unsigned*)((char*)UVl + by) = l; }
            }
        }
        __syncthreads();

        // MFMA: out[px][ch] for this wave's 16-ch tile; K = 128 cells
        f32x4 accO = {0.f, 0.f, 0.f, 0.f};
        #pragma unroll
        for (int ks = 0; ks < 4; ++ks) {
            const int kcol = ks * 32 + kb8;
            bf16x8 wh = ldfrag(Wh, lr, kcol, 256);
            bf16x8 wl = ldfrag(Wl, lr, kcol, 256);
            bf16x8 vh = ldfrag(UVh, wave * 16 + lr, kcol, 256);
            bf16x8 vl = ldfrag(UVl, wave * 16 + lr, kcol, 256);
            accO = __builtin_amdgcn_mfma_f32_16x16x32_bf16(wh, vh, accO, 0, 0, 0);
            accO = __builtin_amdgcn_mfma_f32_16x16x32_bf16(wh, vl, accO, 0, 0, 0);
            accO = __builtin_amdgcn_mfma_f32_16x16x32_bf16(wl, vh, accO, 0, 0, 0);
        }
        // store this chunk's channels
        {
            const int ch = nc * 64 + wave * 16 + lr;
            const int mrow = (lane >> 4) << 2;
            #pragma unroll
            for (int rr = 0; rr < 4; ++rr) {
                const int px = mrow + rr;
                const int a = px >> 3, bb = px & 7;
                out[(((size_t)b * HO_ + (i0 + a)) * WO_ + (j0 + bb)) * C_ + ch] = accO[rr];
            }
        }
        __syncthreads();   // before next chunk overwrites Vt
    }
}

extern "C" void kernel_launch(void* const* d_in, const int* in_sizes, int n_in,
                              void* d_out, int out_size, void* d_ws, size_t ws_size,
                              hipStream_t stream) {
    const float* X = (const float*)d_in[0];
    float* outp    = (float*)d_out;
    hipLaunchKernelGGL(convnd_attn_kernel,
                       dim3(GRID), dim3(256), 0, stream, X, outp);
}

// Round 6
// 91.644 us; speedup vs baseline: 1.1182x; 1.1182x over previous
//
#include <hip/hip_runtime.h>

#define B_   4
#define H_   64
#define W_   64
#define C_   256
#define HO_  58
#define WO_  58
#define TI_  29     // 2-row tiles (58 = 2*29)
#define TJ_  8      // 8-col tiles: j0 = 0,8,...,48,50 (last overlaps, benign dup writes)
#define GRID (B_ * TI_ * TJ_)   // 928 = 8 * 116

typedef __attribute__((ext_vector_type(8))) short bf16x8;   // 8 bf16 = 4 VGPR
typedef __attribute__((ext_vector_type(4))) float f32x4;

// Truncation-split two fp32 into packed hi/lo bf16 dwords (lo16 = first elem).
__device__ __forceinline__ void split2(float a, float b, unsigned& hi, unsigned& lo) {
    unsigned ua = __builtin_bit_cast(unsigned, a);
    unsigned ub = __builtin_bit_cast(unsigned, b);
    hi = (ua >> 16) | (ub & 0xFFFF0000u);
    float ra = a - __builtin_bit_cast(float, ua & 0xFFFF0000u);
    float rb = b - __builtin_bit_cast(float, ub & 0xFFFF0000u);
    lo = (__builtin_bit_cast(unsigned, ra) >> 16) |
         (__builtin_bit_cast(unsigned, rb) & 0xFFFF0000u);
}

__device__ __forceinline__ void split8(const float* v, bf16x8& h, bf16x8& l) {
    uint4 hu, lu;
    split2(v[0], v[1], hu.x, lu.x);
    split2(v[2], v[3], hu.y, lu.y);
    split2(v[4], v[5], hu.z, lu.z);
    split2(v[6], v[7], hu.w, lu.w);
    h = __builtin_bit_cast(bf16x8, hu);
    l = __builtin_bit_cast(bf16x8, lu);
}

// Swizzled LDS fragment read: row-major [row][K] bf16, 8 contiguous K per lane.
__device__ __forceinline__ bf16x8 ldfrag(const short* arr, int row, int col, int rowBytes) {
    int byte = (row * rowBytes + col * 2) ^ ((row & 7) << 4);
    return *(const bf16x8*)((const char*)arr + byte);
}

__global__ __launch_bounds__(256, 3) void convnd_attn_kernel(const float* __restrict__ X,
                                                             float* __restrict__ out) {
    __shared__ __align__(16) float Spart[4][128][16];   // 32 KB partial scores per wave
    __shared__ __align__(16) short Wh[16 * 128];        // 4 KB weights hi [px][cell] (swz)
    __shared__ __align__(16) short Wl[16 * 128];        // 4 KB weights lo
    __shared__ float psum[16][16];
    __shared__ float rtot[16];

    // XCD-contiguous swizzle (928 = 8*116, exact)
    const int sp  = (blockIdx.x & 7) * 116 + (blockIdx.x >> 3);
    const int tj  = sp & 7;
    const int rst = sp >> 3;
    const int ti  = rst % TI_;
    const int b   = rst / TI_;
    const int i0  = ti * 2;
    const int j0  = (tj < 7) ? tj * 8 : 50;

    const int tid  = threadIdx.x;
    const int wave = tid >> 6;
    const int lane = tid & 63;
    const int lr   = lane & 15;        // fragment m/n index
    const int g    = lane >> 4;        // k-octet group 0..3
    const int kb8  = g << 3;

    const float* base = X + (size_t)b * (H_ * W_ * C_);

    // ---- Q fragments in registers: this wave's 64-ch slice, all 16 px ----
    // B-frag: lane holds px = lr, channels wave*64 + ks*32 + g*8 .. +8
    bf16x8 qh[2], ql[2];
    {
        const int aq = lr >> 3, bq = lr & 7;
        const float* qp = base + (((i0 + aq + 3) * W_) + (j0 + bq + 3)) * C_
                        + wave * 64 + kb8;
        #pragma unroll
        for (int ks = 0; ks < 2; ++ks) {
            float v[8];
            float4 x0 = *(const float4*)(qp + ks * 32);
            float4 x1 = *(const float4*)(qp + ks * 32 + 4);
            v[0]=x0.x*0.0625f; v[1]=x0.y*0.0625f; v[2]=x0.z*0.0625f; v[3]=x0.w*0.0625f;
            v[4]=x1.x*0.0625f; v[5]=x1.y*0.0625f; v[6]=x1.z*0.0625f; v[7]=x1.w*0.0625f;
            split8(v, qh[ks], ql[ks]);
        }
    }

    // ---- Phase 1: partial S^T[cell][px] over this wave's ch slice. No LDS, no barriers.
    // A-frag: lane holds cell = 16t + lr (tile t = union row, lr = union col), same ch octet.
    f32x4 accS[8];
    #pragma unroll
    for (int t = 0; t < 8; ++t) accS[t] = (f32x4){0.f, 0.f, 0.f, 0.f};

    const int dj13 = (lr < 13) ? lr : 13;   // cols 14,15 are pad (clamped; masked later)
    const float* up0 = base + (j0 + dj13) * C_ + wave * 64 + kb8;
    #pragma unroll
    for (int t = 0; t < 8; ++t) {
        const float* ur = up0 + (size_t)(i0 + t) * (W_ * C_);
        #pragma unroll
        for (int ks = 0; ks < 2; ++ks) {
            float v[8];
            float4 x0 = *(const float4*)(ur + ks * 32);
            float4 x1 = *(const float4*)(ur + ks * 32 + 4);
            v[0]=x0.x; v[1]=x0.y; v[2]=x0.z; v[3]=x0.w;
            v[4]=x1.x; v[5]=x1.y; v[6]=x1.z; v[7]=x1.w;
            bf16x8 uh, ul;
            split8(v, uh, ul);
            accS[t] = __builtin_amdgcn_mfma_f32_16x16x32_bf16(uh, qh[ks], accS[t], 0, 0, 0);
            accS[t] = __builtin_amdgcn_mfma_f32_16x16x32_bf16(uh, ql[ks], accS[t], 0, 0, 0);
            accS[t] = __builtin_amdgcn_mfma_f32_16x16x32_bf16(ul, qh[ks], accS[t], 0, 0, 0);
        }
    }
    // D layout: cell-row = 16t + g*4 + rr, px-col = lr
    #pragma unroll
    for (int t = 0; t < 8; ++t) {
        #pragma unroll
        for (int rr = 0; rr < 4; ++rr)
            Spart[wave][t * 16 + g * 4 + rr][lr] = accS[t][rr];
    }
    __syncthreads();   // barrier 1

    // ---- Softmax: thread owns (px = tid&15, cells seg*8..+7). Scores ~N(0,1): no max-sub.
    const int spx = tid & 15, seg = tid >> 4;
    {
        const int sa = spx >> 3, sb = spx & 7;
        float e[8]; float ps = 0.f;
        #pragma unroll
        for (int k = 0; k < 8; ++k) {
            const int cell = seg * 8 + k;
            const int di = (cell >> 4) - sa, dj = (cell & 15) - sb;
            const bool valid = (di >= 0) & (di <= 6) & (dj >= 0) & (dj <= 6)
                               & !((di == 3) & (dj == 3));
            const float s = Spart[0][cell][spx] + Spart[1][cell][spx]
                          + Spart[2][cell][spx] + Spart[3][cell][spx];
            e[k] = valid ? __expf(s) : 0.f;
            ps += e[k];
        }
        psum[seg][spx] = ps;
        __syncthreads();   // barrier 2
        if (tid < 16) {
            float t2 = 0.f;
            #pragma unroll
            for (int s2 = 0; s2 < 16; ++s2) t2 += psum[s2][tid];
            rtot[tid] = 1.0f / t2;
        }
        __syncthreads();   // barrier 3
        const float rt = rtot[spx];
        unsigned h0,h1,h2,h3, l0,l1,l2,l3;
        split2(e[0]*rt, e[1]*rt, h0, l0);
        split2(e[2]*rt, e[3]*rt, h1, l1);
        split2(e[4]*rt, e[5]*rt, h2, l2);
        split2(e[6]*rt, e[7]*rt, h3, l3);
        const int wb = (spx * 256 + seg * 16) ^ ((spx & 7) << 4);
        *(uint4*)((char*)Wh + wb) = make_uint4(h0, h1, h2, h3);
        *(uint4*)((char*)Wl + wb) = make_uint4(l0, l1, l2, l3);
    }
    __syncthreads();   // barrier 4 (last)

    // ---- Phase 3: PV. A = W[px][cell] from LDS (hoisted); B = V^T gathered from global.
    bf16x8 wfh[4], wfl[4];
    #pragma unroll
    for (int ks = 0; ks < 4; ++ks) {
        wfh[ks] = ldfrag(Wh, lr, ks * 32 + kb8, 256);
        wfl[ks] = ldfrag(Wl, lr, ks * 32 + kb8, 256);
    }

    #pragma unroll
    for (int cc = 0; cc < 4; ++cc) {
        const int ch = (wave * 4 + cc) * 16 + lr;   // wave's 64-ch slice, tile cc
        f32x4 accO = {0.f, 0.f, 0.f, 0.f};
        #pragma unroll
        for (int ks = 0; ks < 4; ++ks) {
            // B-frag: lane holds ch, cells ks*32 + g*8 + e (di = ks*2 + (g>>1), dj = (g&1)*8 + e)
            const int di  = ks * 2 + (g >> 1);
            const int dj0 = (g & 1) * 8;
            const float* vb = base + (((i0 + di) * W_) + j0) * C_ + ch;
            float v[8];
            #pragma unroll
            for (int e2 = 0; e2 < 8; ++e2) {
                const int dj = (dj0 + e2 < 13) ? dj0 + e2 : 13;   // pad cells clamped (W=0)
                v[e2] = vb[dj * C_];
            }
            bf16x8 vh, vl;
            split8(v, vh, vl);
            accO = __builtin_amdgcn_mfma_f32_16x16x32_bf16(wfh[ks], vh, accO, 0, 0, 0);
            accO = __builtin_amdgcn_mfma_f32_16x16x32_bf16(wfh[ks], vl, accO, 0, 0, 0);
            accO = __builtin_amdgcn_mfma_f32_16x16x32_bf16(wfl[ks], vh, accO, 0, 0, 0);
        }
        // D layout: px-row = g*4 + rr, ch-col = lr (inside ch)
        #pragma unroll
        for (int rr = 0; rr < 4; ++rr) {
            const int px = g * 4 + rr;
            const int aa = px >> 3, bb = px & 7;
            out[(((size_t)b * HO_ + (i0 + aa)) * WO_ + (j0 + bb)) * C_ + ch] = accO[rr];
        }
    }
}

extern "C" void kernel_launch(void* const* d_in, const int* in_sizes, int n_in,
                              void* d_out, int out_size, void* d_ws, size_t ws_size,
                              hipStream_t stream) {
    const float* X = (const float*)d_in[0];
    float* outp    = (float*)d_out;
    hipLaunchKernelGGL(convnd_attn_kernel,
                       dim3(GRID), dim3(256), 0, stream, X, outp);
}

// Round 7
// 87.771 us; speedup vs baseline: 1.1675x; 1.0441x over previous
//
#include <hip/hip_runtime.h>

#define B_   4
#define H_   64
#define W_   64
#define C_   256
#define HO_  58
#define WO_  58
#define TI_  29     // 2-row tiles (58 = 2*29)
#define TJ_  8      // 8-col tiles: j0 = 0,8,...,48,50 (last overlaps, benign dup writes)
#define GRID (B_ * TI_ * TJ_)   // 928 = 8 * 116

typedef __attribute__((ext_vector_type(8))) short bf16x8;   // 8 bf16 = 4 VGPR
typedef __attribute__((ext_vector_type(4))) float f32x4;

// RTN pack: dword = (bf16(a) in lo16) | (bf16(b) in hi16). No builtin on gfx950 (m240).
__device__ __forceinline__ unsigned cvtpk(float a, float b) {
    unsigned r;
    asm("v_cvt_pk_bf16_f32 %0, %1, %2" : "=v"(r) : "v"(a), "v"(b));
    return r;
}
__device__ __forceinline__ float lo16f(unsigned h) { return __builtin_bit_cast(float, h << 16); }
__device__ __forceinline__ float hi16f(unsigned h) { return __builtin_bit_cast(float, h & 0xFFFF0000u); }

// Split 8 fp32 -> hi/lo bf16x8 via cvt_pk (RTN both terms; residual exact to ~2^-16 rel).
__device__ __forceinline__ void split8cvt(const float* v, bf16x8& h, bf16x8& l) {
    uint4 hu, lu;
    hu.x = cvtpk(v[0], v[1]); hu.y = cvtpk(v[2], v[3]);
    hu.z = cvtpk(v[4], v[5]); hu.w = cvtpk(v[6], v[7]);
    lu.x = cvtpk(v[0] - lo16f(hu.x), v[1] - hi16f(hu.x));
    lu.y = cvtpk(v[2] - lo16f(hu.y), v[3] - hi16f(hu.y));
    lu.z = cvtpk(v[4] - lo16f(hu.z), v[5] - hi16f(hu.z));
    lu.w = cvtpk(v[6] - lo16f(hu.w), v[7] - hi16f(hu.w));
    h = __builtin_bit_cast(bf16x8, hu);
    l = __builtin_bit_cast(bf16x8, lu);
}

// Swizzled LDS fragment read: row-major [row][K] bf16, 8 contiguous K per lane.
__device__ __forceinline__ bf16x8 ldfrag(const short* arr, int row, int col, int rowBytes) {
    int byte = (row * rowBytes + col * 2) ^ ((row & 7) << 4);
    return *(const bf16x8*)((const char*)arr + byte);
}

__global__ __launch_bounds__(256, 4) void convnd_attn_kernel(const float* __restrict__ X,
                                                             float* __restrict__ out) {
    // 33.9 KB -> 4 blocks/CU. Wh/Wl alias Spart (W written after barrier 3,
    // Spart last read before barrier 2 -> barrier-ordered, no race).
    __shared__ __align__(16) char smem[32768 + 1024 + 64];
    float (*Spart)[128][16] = reinterpret_cast<float (*)[128][16]>(smem);  // [4][128][16]
    short* Wh = reinterpret_cast<short*>(smem);                            // 4 KB (aliases)
    short* Wl = reinterpret_cast<short*>(smem + 4096);                     // 4 KB (aliases)
    float (*psum)[16] = reinterpret_cast<float (*)[16]>(smem + 32768);     // [16][16]
    float* rtot = reinterpret_cast<float*>(smem + 32768 + 1024);           // [16]

    // XCD-contiguous swizzle (928 = 8*116, exact)
    const int sp  = (blockIdx.x & 7) * 116 + (blockIdx.x >> 3);
    const int tj  = sp & 7;
    const int rst = sp >> 3;
    const int ti  = rst % TI_;
    const int b   = rst / TI_;
    const int i0  = ti * 2;
    const int j0  = (tj < 7) ? tj * 8 : 50;

    const int tid  = threadIdx.x;
    const int wave = tid >> 6;
    const int lane = tid & 63;
    const int lr   = lane & 15;        // fragment m/n index
    const int g    = lane >> 4;        // k-octet group 0..3
    const int kb8  = g << 3;

    const float* base = X + (size_t)b * (H_ * W_ * C_);

    // ---- Q fragments in registers: wave's 64-ch slice, all 16 px, pre-scaled 1/16.
    bf16x8 qh[2], ql[2];
    {
        const int aq = lr >> 3, bq = lr & 7;
        const float* qp = base + (((i0 + aq + 3) * W_) + (j0 + bq + 3)) * C_
                        + wave * 64 + kb8;
        #pragma unroll
        for (int ks = 0; ks < 2; ++ks) {
            float4 x0 = *(const float4*)(qp + ks * 32);
            float4 x1 = *(const float4*)(qp + ks * 32 + 4);
            float v[8] = {x0.x*0.0625f, x0.y*0.0625f, x0.z*0.0625f, x0.w*0.0625f,
                          x1.x*0.0625f, x1.y*0.0625f, x1.z*0.0625f, x1.w*0.0625f};
            split8cvt(v, qh[ks], ql[ks]);
        }
    }

    // ---- Phase 1: partial S^T[cell][px] over this wave's ch slice. Depth-2 prefetch.
    f32x4 accS[8];
    #pragma unroll
    for (int t = 0; t < 8; ++t) accS[t] = (f32x4){0.f, 0.f, 0.f, 0.f};

    const int dj13 = (lr < 13) ? lr : 13;   // cols 14,15 are pad (clamped; masked later)
    const float* up0 = base + (size_t)i0 * (W_ * C_) + (j0 + dj13) * C_ + wave * 64 + kb8;

    float4 pfa[2], pfb[2];
    pfa[0] = *(const float4*)(up0);                   // it=0: t=0, ks=0
    pfb[0] = *(const float4*)(up0 + 4);
    pfa[1] = *(const float4*)(up0 + 32);              // it=1: t=0, ks=1
    pfb[1] = *(const float4*)(up0 + 36);
    #pragma unroll
    for (int it = 0; it < 16; ++it) {
        const int t = it >> 1;                        // ks = it & 1
        float v[8];
        { float4 c0 = pfa[it & 1], c1 = pfb[it & 1];
          v[0]=c0.x; v[1]=c0.y; v[2]=c0.z; v[3]=c0.w;
          v[4]=c1.x; v[5]=c1.y; v[6]=c1.z; v[7]=c1.w; }
        if (it + 2 < 16) {
            const float* p = up0 + ((it + 2) >> 1) * (W_ * C_) + ((it + 2) & 1) * 32;
            pfa[it & 1] = *(const float4*)(p);
            pfb[it & 1] = *(const float4*)(p + 4);
        }
        bf16x8 uh, ul;
        split8cvt(v, uh, ul);
        accS[t] = __builtin_amdgcn_mfma_f32_16x16x32_bf16(uh, qh[it & 1], accS[t], 0, 0, 0);
        accS[t] = __builtin_amdgcn_mfma_f32_16x16x32_bf16(uh, ql[it & 1], accS[t], 0, 0, 0);
        accS[t] = __builtin_amdgcn_mfma_f32_16x16x32_bf16(ul, qh[it & 1], accS[t], 0, 0, 0);
    }
    // D layout: cell-row = 16t + g*4 + rr, px-col = lr
    #pragma unroll
    for (int t = 0; t < 8; ++t) {
        #pragma unroll
        for (int rr = 0; rr < 4; ++rr)
            Spart[wave][t * 16 + g * 4 + rr][lr] = accS[t][rr];
    }
    __syncthreads();   // barrier 1

    // ---- Softmax: thread owns (px = tid&15, cells seg*8..+7). Scores ~N(0,1): no max-sub.
    const int spx = tid & 15, seg = tid >> 4;
    {
        const int sa = spx >> 3, sb = spx & 7;
        float e[8]; float ps = 0.f;
        #pragma unroll
        for (int k = 0; k < 8; ++k) {
            const int cell = seg * 8 + k;
            const int di = (cell >> 4) - sa, dj = (cell & 15) - sb;
            const bool valid = (di >= 0) & (di <= 6) & (dj >= 0) & (dj <= 6)
                               & !((di == 3) & (dj == 3));
            const float s = Spart[0][cell][spx] + Spart[1][cell][spx]
                          + Spart[2][cell][spx] + Spart[3][cell][spx];
            e[k] = valid ? __expf(s) : 0.f;
            ps += e[k];
        }
        psum[seg][spx] = ps;
        __syncthreads();   // barrier 2
        if (tid < 16) {
            float t2 = 0.f;
            #pragma unroll
            for (int s2 = 0; s2 < 16; ++s2) t2 += psum[s2][tid];
            rtot[tid] = 1.0f / t2;
        }
        __syncthreads();   // barrier 3
        const float rt = rtot[spx];
        // W = e*rt split hi/lo via cvt_pk (RTN); writes alias dead Spart region.
        uint4 hu, lu;
        float w0, w1;
        w0 = e[0]*rt; w1 = e[1]*rt; hu.x = cvtpk(w0, w1);
        lu.x = cvtpk(w0 - lo16f(hu.x), w1 - hi16f(hu.x));
        w0 = e[2]*rt; w1 = e[3]*rt; hu.y = cvtpk(w0, w1);
        lu.y = cvtpk(w0 - lo16f(hu.y), w1 - hi16f(hu.y));
        w0 = e[4]*rt; w1 = e[5]*rt; hu.z = cvtpk(w0, w1);
        lu.z = cvtpk(w0 - lo16f(hu.z), w1 - hi16f(hu.z));
        w0 = e[6]*rt; w1 = e[7]*rt; hu.w = cvtpk(w0, w1);
        lu.w = cvtpk(w0 - lo16f(hu.w), w1 - hi16f(hu.w));
        const int wb = (spx * 256 + seg * 16) ^ ((spx & 7) << 4);
        *(uint4*)((char*)Wh + wb) = make_uint4(hu.x, hu.y, hu.z, hu.w);
        *(uint4*)((char*)Wl + wb) = make_uint4(lu.x, lu.y, lu.z, lu.w);
    }
    __syncthreads();   // barrier 4 (last)

    // ---- Phase 3: PV. A = W[px][cell] (hoisted from LDS); B = V^T gathered, depth-2 prefetch.
    bf16x8 wfh[4], wfl[4];
    #pragma unroll
    for (int ks = 0; ks < 4; ++ks) {
        wfh[ks] = ldfrag(Wh, lr, ks * 32 + kb8, 256);
        wfl[ks] = ldfrag(Wl, lr, ks * 32 + kb8, 256);
    }

    // Per-lane gather geometry: cell = ks*32 + g*8 + e2 -> di = ks*2 + (g>>1), dj = (g&1)*8 + e2.
    // voff[e2] = ((g>>1)*W + dj_clamped)*C  (float index); per-iter adds compile-time consts.
    int voff[8];
    {
        const int dj0 = (g & 1) * 8;
        #pragma unroll
        for (int e2 = 0; e2 < 8; ++e2) {
            int dj = dj0 + e2; if (dj > 13) dj = 13;      // pad cells (weight 0)
            voff[e2] = (g >> 1) * (W_ * C_) + dj * C_;
        }
    }
    const float* vbase = base + (size_t)i0 * (W_ * C_) + j0 * C_ + wave * 64 + lr;

    f32x4 accO[4];
    #pragma unroll
    for (int cc = 0; cc < 4; ++cc) accO[cc] = (f32x4){0.f, 0.f, 0.f, 0.f};

    float pv[2][8];
    // preload it=0 (ks=0,cc=0) and it=1 (ks=0,cc=1)
    #pragma unroll
    for (int e2 = 0; e2 < 8; ++e2) pv[0][e2] = vbase[voff[e2]];
    #pragma unroll
    for (int e2 = 0; e2 < 8; ++e2) pv[1][e2] = (vbase + 16)[voff[e2]];

    #pragma unroll
    for (int it = 0; it < 16; ++it) {
        const int ks = it >> 2, cc = it & 3;
        float v[8];
        #pragma unroll
        for (int e2 = 0; e2 < 8; ++e2) v[e2] = pv[it & 1][e2];
        if (it + 2 < 16) {
            const int ks2 = (it + 2) >> 2, cc2 = (it + 2) & 3;
            const float* p = vbase + (size_t)(ks2 * 2) * (W_ * C_) + cc2 * 16;
            #pragma unroll
            for (int e2 = 0; e2 < 8; ++e2) pv[it & 1][e2] = p[voff[e2]];
        }
        bf16x8 vh, vl;
        split8cvt(v, vh, vl);
        accO[cc] = __builtin_amdgcn_mfma_f32_16x16x32_bf16(wfh[ks], vh, accO[cc], 0, 0, 0);
        accO[cc] = __builtin_amdgcn_mfma_f32_16x16x32_bf16(wfh[ks], vl, accO[cc], 0, 0, 0);
        accO[cc] = __builtin_amdgcn_mfma_f32_16x16x32_bf16(wfl[ks], vh, accO[cc], 0, 0, 0);
    }

    // D layout: px-row = g*4 + rr, ch-col = lr (within the cc-th 16-ch tile)
    #pragma unroll
    for (int cc = 0; cc < 4; ++cc) {
        const int ch = (wave * 4 + cc) * 16 + lr;
        #pragma unroll
        for (int rr = 0; rr < 4; ++rr) {
            const int px = g * 4 + rr;
            const int aa = px >> 3, bb = px & 7;
            out[(((size_t)b * HO_ + (i0 + aa)) * WO_ + (j0 + bb)) * C_ + ch] = accO[cc][rr];
        }
    }
}

extern "C" void kernel_launch(void* const* d_in, const int* in_sizes, int n_in,
                              void* d_out, int out_size, void* d_ws, size_t ws_size,
                              hipStream_t stream) {
    const float* X = (const float*)d_in[0];
    float* outp    = (float*)d_out;
    hipLaunchKernelGGL(convnd_attn_kernel,
                       dim3(GRID), dim3(256), 0, stream, X, outp);
}